// Round 6
// baseline (299.306 us; speedup 1.0000x reference)
//
#include <hip/hip_runtime.h>
#include <math.h>

#define EPS 1e-7f

constexpr int Nn = 4, Hh = 1080, Ww = 1920;
constexpr int HW = Hh * Ww;
constexpr int TOTAL = Nn * HW;

constexpr int TW = 32, TH = 32;          // output tile
constexpr int TXN = 60, TYN = 34;        // 60*32=1920 exact, 34*32=1088>1080
constexpr int REACH = 5;                 // |flow|<=5 handled by gather pass
constexpr float NEAR_MAX = 5.0f;
constexpr int WINW = TW + 2 * REACH;     // 42
constexpr int WINH = TH + 2 * REACH;     // 42
constexpr int WINSZ = WINW * WINH;       // 1764
constexpr int NCH = TH + 1;              // 33 cell rows (ly0 in [-1,31])
constexpr int NCWc = TW + 1;             // 33 cell cols
constexpr int NCELLS = NCWc * NCH;       // 1089
constexpr int NOFF = NCELLS + 1;         // 1090 = 218*5 exactly
constexpr int PADL = 8;                  // left pad -> 4-aligned chunks
constexpr int NCHUNK = 12;               // 48-px padded row = 12 float4 chunks
constexpr int TOTCH = NCHUNK * WINH;     // 504 chunks per tile window
constexpr float INV64K = 1.52587890625e-5f;  // 2^-16

// ---------------- pass 1: rare far sources (|flow|>5) -> compact global list ----------------

__global__ __launch_bounds__(256) void far_scatter(
    const float* __restrict__ tenIn, const float* __restrict__ tenFlow,
    const float* __restrict__ tenMetric,
    unsigned int* __restrict__ farCount, float* __restrict__ farList,
    unsigned int farCap)
{
    int q = blockIdx.x * 256 + threadIdx.x;     // quad index; TOTAL % 4 == 0
    if (q >= TOTAL / 4) return;
    int n  = q / (HW / 4);
    int p  = (q - n * (HW / 4)) * 4;            // base pixel, row-aligned (Ww%4==0)

    const float* __restrict__ f0 = tenFlow + (size_t)(n * 2 + 0) * HW;
    const float* __restrict__ f1 = f0 + HW;
    float4 fx4 = *(const float4*)(f0 + p);
    float4 fy4 = *(const float4*)(f1 + p);

    float mx = fmaxf(fmaxf(fabsf(fx4.x), fabsf(fx4.y)), fmaxf(fabsf(fx4.z), fabsf(fx4.w)));
    float my = fmaxf(fmaxf(fabsf(fy4.x), fabsf(fy4.y)), fmaxf(fabsf(fy4.z), fabsf(fy4.w)));
    if (!(mx > NEAR_MAX || my > NEAR_MAX)) return;

    int y = p / Ww;
    int xbase = p - y * Ww;
    float fxa[4] = {fx4.x, fx4.y, fx4.z, fx4.w};
    float fya[4] = {fy4.x, fy4.y, fy4.z, fy4.w};

#pragma unroll
    for (int k = 0; k < 4; ++k) {
        float fxv = fxa[k], fyv = fya[k];
        if (!(fabsf(fxv) > NEAR_MAX || fabsf(fyv) > NEAR_MAX)) continue;  // near or NaN
        float fx = (float)(xbase + k) + fxv;
        float fy = (float)y + fyv;
        if (!isfinite(fx) || !isfinite(fy)) continue;
        if (!(fx > -1.0f && fx < (float)Ww && fy > -1.0f && fy < (float)Hh)) continue;

        int pp = p + k;
        float m  = expf(tenMetric[(size_t)n * HW + pp]);
        float v0 = tenIn[((size_t)n * 3 + 0) * HW + pp] * m;
        float v1 = tenIn[((size_t)n * 3 + 1) * HW + pp] * m;
        float v2 = tenIn[((size_t)n * 3 + 2) * HW + pp] * m;

        unsigned int slot = atomicAdd(farCount, 1u);
        if (slot < farCap) {
            float* ep = farList + (size_t)slot * 8;
            ep[0] = __int_as_float(n);
            ep[1] = fx; ep[2] = fy;
            ep[3] = v0; ep[4] = v1; ep[5] = v2; ep[6] = m;
            ep[7] = 0.0f;
        }
    }
}

// ---------------- pass 2: CSR-bucketed gather ----------------
// Column-major cells: ci = (lx0+1)*33 + (ly0+1). A thread's two cell rows per
// column are CSR-contiguous -> 5 ranges (not 10), row weight via s<mid.
// All global loads hoisted to phase 1; phase 3 is pure reg->LDS scatter.

__global__ __launch_bounds__(256, 4) void gather_splat(
    const float* __restrict__ tenIn, const float* __restrict__ tenFlow,
    const float* __restrict__ tenMetric,
    const float* __restrict__ farList, const unsigned int* __restrict__ farCount,
    unsigned int farCap, float* __restrict__ out)
{
    __shared__ float4 sVal[WINSZ];           // (v0*m, v1*m, v2*m, m)   28224 B
    __shared__ unsigned int sPack[WINSZ];    // fracx | wy1<<16          7056 B
    __shared__ unsigned int sOff[NOFF];      // counts -> CSR offsets    4360 B
    __shared__ unsigned int sWsum[8];
    // total 39672 B -> 4 blocks/CU

    const int tx = blockIdx.x, ty = blockIdx.y, n = blockIdx.z;
    const int tX = tx * TW, tY = ty * TH;
    const int tid = threadIdx.x;

    for (int j = tid; j < NOFF; j += 256) sOff[j] = 0u;
    __syncthreads();

    const float* __restrict__ f0 = tenFlow   + (size_t)(n * 2 + 0) * HW;
    const float* __restrict__ f1 = tenFlow   + (size_t)(n * 2 + 1) * HW;
    const float* __restrict__ mp = tenMetric + (size_t)n * HW;
    const float* __restrict__ i0 = tenIn + (size_t)(n * 3 + 0) * HW;
    const float* __restrict__ i1 = tenIn + (size_t)(n * 3 + 1) * HW;
    const float* __restrict__ i2 = tenIn + (size_t)(n * 3 + 2) * HW;

    // ---- phase 1: all 6 planes float4-loaded, bucket-count, values in regs ----
    unsigned int pk[2][4];    // sic<<16 | ci ; 0xFFFFFFFF = invalid
    unsigned int spw[2][4];   // packed (fracx, wy1)
    float rv0[2][4], rv1[2][4], rv2[2][4], rvm[2][4];

#pragma unroll
    for (int cc = 0; cc < 2; ++cc) {
#pragma unroll
        for (int k = 0; k < 4; ++k) pk[cc][k] = 0xFFFFFFFFu;
        int cidx = tid + cc * 256;
        if (cidx >= TOTCH) continue;
        int wy = cidx / NCHUNK;
        int cx = cidx - wy * NCHUNK;
        int sy = tY - REACH + wy;
        int gx = tX - PADL + cx * 4;              // 4-aligned; chunk fully in or out
        if (sy < 0 || sy >= Hh || gx < 0 || gx > Ww - 4) continue;
        int p = sy * Ww + gx;
        float4 fx4 = *(const float4*)(f0 + p);
        float4 fy4 = *(const float4*)(f1 + p);
        float4 m4  = *(const float4*)(mp + p);
        float4 a04 = *(const float4*)(i0 + p);
        float4 a14 = *(const float4*)(i1 + p);
        float4 a24 = *(const float4*)(i2 + p);
        float fxa[4] = {fx4.x, fx4.y, fx4.z, fx4.w};
        float fya[4] = {fy4.x, fy4.y, fy4.z, fy4.w};
        float ma[4]  = {m4.x,  m4.y,  m4.z,  m4.w};
        float a0a[4] = {a04.x, a04.y, a04.z, a04.w};
        float a1a[4] = {a14.x, a14.y, a14.z, a14.w};
        float a2a[4] = {a24.x, a24.y, a24.z, a24.w};
#pragma unroll
        for (int k = 0; k < 4; ++k) {
            int x = gx + k;
            if (x < tX - REACH || x >= tX + TW + REACH) continue;  // padding px
            float fxv = fxa[k], fyv = fya[k];
            if (!(fabsf(fxv) <= NEAR_MAX && fabsf(fyv) <= NEAR_MAX)) continue;  // NaN fails
            float fx = (float)x + fxv;
            float fy = (float)sy + fyv;
            float flx = floorf(fx), fly = floorf(fy);
            int lx0 = (int)flx - tX;
            int ly0 = (int)fly - tY;
            if (lx0 < -1 || lx0 >= TW || ly0 < -1 || ly0 >= TH) continue;
            int ci = (lx0 + 1) * NCH + (ly0 + 1);          // column-major
            unsigned int sic = atomicAdd(&sOff[ci], 1u);   // ds_add_rtn_u32
            pk[cc][k] = (sic << 16) | (unsigned int)ci;
            spw[cc][k] = __float2uint_rz((fx - flx) * 65536.0f)
                       | (__float2uint_rz((fy - fly) * 65536.0f) << 16);
            float m = expf(ma[k]);
            rv0[cc][k] = a0a[k] * m;
            rv1[cc][k] = a1a[k] * m;
            rv2[cc][k] = a2a[k] * m;
            rvm[cc][k] = m;
        }
    }
    __syncthreads();

    // ---- phase 2: exclusive prefix sum over sOff[0..NOFF) (218 threads x 5) ----
    unsigned int c0v = 0, c1v = 0, c2v = 0, c3v = 0, c4v = 0;
    if (tid < 218) {
        int base = tid * 5;
        c0v = sOff[base];     c1v = sOff[base + 1]; c2v = sOff[base + 2];
        c3v = sOff[base + 3]; c4v = sOff[base + 4];
    }
    unsigned int tsum = c0v + c1v + c2v + c3v + c4v;
    unsigned int incl = tsum;
#pragma unroll
    for (int d = 1; d < 64; d <<= 1) {
        unsigned int v = __shfl_up(incl, d);
        if ((tid & 63) >= d) incl += v;
    }
    const int wv = tid >> 6;
    if ((tid & 63) == 63) sWsum[wv] = incl;
    __syncthreads();                 // orders count-reads before off-writes too
    unsigned int woff = 0;
    {
        unsigned int w0 = sWsum[0], w1 = sWsum[1], w2 = sWsum[2];
        if (wv > 0) woff += w0;
        if (wv > 1) woff += w1;
        if (wv > 2) woff += w2;
    }
    unsigned int texcl = woff + incl - tsum;
    if (tid < 218) {
        int base = tid * 5;
        unsigned int o0 = texcl, o1 = o0 + c0v, o2 = o1 + c1v, o3 = o2 + c2v, o4 = o3 + c3v;
        sOff[base] = o0; sOff[base + 1] = o1; sOff[base + 2] = o2;
        sOff[base + 3] = o3; sOff[base + 4] = o4;
    }
    __syncthreads();

    // ---- phase 3: pure reg->LDS scatter ----
#pragma unroll
    for (int cc = 0; cc < 2; ++cc) {
#pragma unroll
        for (int k = 0; k < 4; ++k) {
            unsigned int p_ = pk[cc][k];
            if (p_ == 0xFFFFFFFFu) continue;
            unsigned int ci  = p_ & 0xFFFFu;
            unsigned int sic = p_ >> 16;
            unsigned int slot = sOff[ci] + sic;
            sPack[slot] = spw[cc][k];
            sVal[slot]  = make_float4(rv0[cc][k], rv1[cc][k], rv2[cc][k], rvm[cc][k]);
        }
    }
    __syncthreads();

    // ---- phase 4: 5 contiguous row-pair ranges; row weight via s<mid ----
    const int r   = tid >> 3;        // 0..31 output row
    const int g   = tid & 7;
    const int cc0 = g * 4;           // first owned col

    float4 acc0 = make_float4(0.f, 0.f, 0.f, 0.f);
    float4 acc1 = make_float4(0.f, 0.f, 0.f, 0.f);
    float4 acc2 = make_float4(0.f, 0.f, 0.f, 0.f);
    float4 acc3 = make_float4(0.f, 0.f, 0.f, 0.f);

    // column j (cell col cc0+j; sources lx0 = cc0+j-1): L -> acc[j-1], R -> acc[j]
    // cell rows r (ly0=r-1, ay=wy1) then r+1 (ly0=r, ay=1-wy1), split at mid.
#define COLRANGE(J, HASL, HASR, ACCL, ACCR)                               \
    {                                                                     \
        const int cbase = (cc0 + (J)) * NCH + r;                          \
        unsigned int lo = sOff[cbase], md = sOff[cbase + 1],              \
                     hi = sOff[cbase + 2];                                \
        for (unsigned int s = lo; s < hi; ++s) {                          \
            unsigned int pw = sPack[s];                                   \
            float4 v = sVal[s];                                           \
            float fracx = (float)(pw & 0xFFFFu) * INV64K;                 \
            float wy1q  = (float)(pw >> 16)     * INV64K;                 \
            float ay = (s < md) ? wy1q : (1.0f - wy1q);                   \
            float wr = ay * fracx;                                        \
            float wl = ay - wr;                                           \
            if (HASL) { ACCL.x += v.x*wl; ACCL.y += v.y*wl;               \
                        ACCL.z += v.z*wl; ACCL.w += v.w*wl; }             \
            if (HASR) { ACCR.x += v.x*wr; ACCR.y += v.y*wr;               \
                        ACCR.z += v.z*wr; ACCR.w += v.w*wr; }             \
        }                                                                 \
    }

    COLRANGE(0, false, true,  acc0, acc0)
    COLRANGE(1, true,  true,  acc0, acc1)
    COLRANGE(2, true,  true,  acc1, acc2)
    COLRANGE(3, true,  true,  acc2, acc3)
    COLRANGE(4, true,  false, acc3, acc0)
#undef COLRANGE

    // ---- epilogue: far-list merge + normalize + write ----
    const int gy = tY + r;
    if (gy >= Hh) return;
    const int gx = tX + cc0;

    unsigned int fc = *farCount;
    if (fc > farCap) fc = farCap;
    const float gyf = (float)gy;
    const float gxf = (float)gx;
    for (unsigned int e = 0; e < fc; ++e) {
        const float* ep = farList + (size_t)e * 8;
        if (__float_as_int(ep[0]) != n) continue;
        float ffx = ep[1], ffy = ep[2];
        float ay = fmaxf(0.f, 1.f - fabsf(ffy - gyf));
        if (ay > 0.f) {
            float fv0 = ep[3], fv1 = ep[4], fv2 = ep[5], fm = ep[6];
            float d = ffx - gxf;
            float ax0 = fmaxf(0.f, 1.f - fabsf(d));
            float ax1 = fmaxf(0.f, 1.f - fabsf(d - 1.f));
            float ax2 = fmaxf(0.f, 1.f - fabsf(d - 2.f));
            float ax3 = fmaxf(0.f, 1.f - fabsf(d - 3.f));
            float w0 = ay * ax0, w1 = ay * ax1, w2 = ay * ax2, w3 = ay * ax3;
            acc0.x += fv0 * w0; acc0.y += fv1 * w0; acc0.z += fv2 * w0; acc0.w += fm * w0;
            acc1.x += fv0 * w1; acc1.y += fv1 * w1; acc1.z += fv2 * w1; acc1.w += fm * w1;
            acc2.x += fv0 * w2; acc2.y += fv1 * w2; acc2.z += fv2 * w2; acc2.w += fm * w2;
            acc3.x += fv0 * w3; acc3.y += fv1 * w3; acc3.z += fv2 * w3; acc3.w += fm * w3;
        }
    }

    const float inv0 = 1.0f / (acc0.w + EPS);
    const float inv1 = 1.0f / (acc1.w + EPS);
    const float inv2 = 1.0f / (acc2.w + EPS);
    const float inv3 = 1.0f / (acc3.w + EPS);

    const size_t pix = (size_t)gy * Ww + gx;   // gx % 4 == 0 -> 16B aligned
    float4 o;
    o = make_float4(acc0.x * inv0, acc1.x * inv1, acc2.x * inv2, acc3.x * inv3);
    *(float4*)(out + ((size_t)n * 3 + 0) * HW + pix) = o;
    o = make_float4(acc0.y * inv0, acc1.y * inv1, acc2.y * inv2, acc3.y * inv3);
    *(float4*)(out + ((size_t)n * 3 + 1) * HW + pix) = o;
    o = make_float4(acc0.z * inv0, acc1.z * inv1, acc2.z * inv2, acc3.z * inv3);
    *(float4*)(out + ((size_t)n * 3 + 2) * HW + pix) = o;
}

extern "C" void kernel_launch(void* const* d_in, const int* in_sizes, int n_in,
                              void* d_out, int out_size, void* d_ws, size_t ws_size,
                              hipStream_t stream) {
    const float* tenIn     = (const float*)d_in[0];
    const float* tenFlow   = (const float*)d_in[1];
    const float* tenMetric = (const float*)d_in[2];
    float* out = (float*)d_out;

    unsigned int* farCount = (unsigned int*)d_ws;
    float* farList = (float*)((char*)d_ws + 64);
    unsigned int farCap = (ws_size > 64) ? (unsigned int)((ws_size - 64) / 32) : 0;

    hipMemsetAsync(d_ws, 0, 64, stream);

    far_scatter<<<(TOTAL / 4 + 255) / 256, 256, 0, stream>>>(
        tenIn, tenFlow, tenMetric, farCount, farList, farCap);

    dim3 grid(TXN, TYN, Nn);
    gather_splat<<<grid, 256, 0, stream>>>(
        tenIn, tenFlow, tenMetric, farList, farCount, farCap, out);
}

// Round 7
// 273.743 us; speedup vs baseline: 1.0934x; 1.0934x over previous
//
#include <hip/hip_runtime.h>
#include <math.h>

#define EPS 1e-7f

constexpr int Nn = 4, Hh = 1080, Ww = 1920;
constexpr int HW = Hh * Ww;
constexpr int TOTAL = Nn * HW;

constexpr int TW = 32, TH = 32;          // output tile
constexpr int TXN = 60, TYN = 34;        // 60*32=1920 exact, 34*32=1088>1080
constexpr int REACH = 5;                 // |flow|<=5 handled by gather pass
constexpr float NEAR_MAX = 5.0f;
constexpr int WINW = TW + 2 * REACH;     // 42
constexpr int WINH = TH + 2 * REACH;     // 42
constexpr int WINSZ = WINW * WINH;       // 1764
constexpr int NCH = TH + 1;              // 33 cell rows (ly0 in [-1,31])
constexpr int NCWc = TW + 1;             // 33 cell cols
constexpr int NCELLS = NCWc * NCH;       // 1089
constexpr int NOFF = NCELLS + 1;         // 1090 = 218*5 exactly
constexpr int PADL = 8;                  // left pad -> 4-aligned chunks
constexpr int NCHUNK = 12;               // 48-px padded row = 12 float4 chunks
constexpr int TOTCH = NCHUNK * WINH;     // 504 chunks per tile window
constexpr int NTILES = TXN * TYN * Nn;   // 8160 = 8 * 1020 exactly
constexpr int NXCD = 8;
constexpr int TPX = NTILES / NXCD;       // 1020 tiles per XCD band
constexpr float INV64K = 1.52587890625e-5f;  // 2^-16

// ---------------- pass 1: rare far sources (|flow|>5) -> compact global list ----------------

__global__ __launch_bounds__(256) void far_scatter(
    const float* __restrict__ tenIn, const float* __restrict__ tenFlow,
    const float* __restrict__ tenMetric,
    unsigned int* __restrict__ farCount, float* __restrict__ farList,
    unsigned int farCap)
{
    int q = blockIdx.x * 256 + threadIdx.x;     // quad index; TOTAL % 4 == 0
    if (q >= TOTAL / 4) return;
    int n  = q / (HW / 4);
    int p  = (q - n * (HW / 4)) * 4;            // base pixel, row-aligned (Ww%4==0)

    const float* __restrict__ f0 = tenFlow + (size_t)(n * 2 + 0) * HW;
    const float* __restrict__ f1 = f0 + HW;
    float4 fx4 = *(const float4*)(f0 + p);
    float4 fy4 = *(const float4*)(f1 + p);

    float mx = fmaxf(fmaxf(fabsf(fx4.x), fabsf(fx4.y)), fmaxf(fabsf(fx4.z), fabsf(fx4.w)));
    float my = fmaxf(fmaxf(fabsf(fy4.x), fabsf(fy4.y)), fmaxf(fabsf(fy4.z), fabsf(fy4.w)));
    if (!(mx > NEAR_MAX || my > NEAR_MAX)) return;

    int y = p / Ww;
    int xbase = p - y * Ww;
    float fxa[4] = {fx4.x, fx4.y, fx4.z, fx4.w};
    float fya[4] = {fy4.x, fy4.y, fy4.z, fy4.w};

#pragma unroll
    for (int k = 0; k < 4; ++k) {
        float fxv = fxa[k], fyv = fya[k];
        if (!(fabsf(fxv) > NEAR_MAX || fabsf(fyv) > NEAR_MAX)) continue;  // near or NaN
        float fx = (float)(xbase + k) + fxv;
        float fy = (float)y + fyv;
        if (!isfinite(fx) || !isfinite(fy)) continue;
        if (!(fx > -1.0f && fx < (float)Ww && fy > -1.0f && fy < (float)Hh)) continue;

        int pp = p + k;
        float m  = expf(tenMetric[(size_t)n * HW + pp]);
        float v0 = tenIn[((size_t)n * 3 + 0) * HW + pp] * m;
        float v1 = tenIn[((size_t)n * 3 + 1) * HW + pp] * m;
        float v2 = tenIn[((size_t)n * 3 + 2) * HW + pp] * m;

        unsigned int slot = atomicAdd(farCount, 1u);
        if (slot < farCap) {
            float* ep = farList + (size_t)slot * 8;
            ep[0] = __int_as_float(n);
            ep[1] = fx; ep[2] = fy;
            ep[3] = v0; ep[4] = v1; ep[5] = v2; ep[6] = m;
            ep[7] = 0.0f;
        }
    }
}

// ---------------- pass 2: CSR-bucketed gather ----------------
// Column-major cells (5 contiguous row-pair ranges). Value loads issued at
// end of phase 1 (condition known) into regs; HBM latency hides under the
// prefix sum. XCD-banded tile swizzle: horizontal neighbors share L2.

__global__ __launch_bounds__(256, 4) void gather_splat(
    const float* __restrict__ tenIn, const float* __restrict__ tenFlow,
    const float* __restrict__ tenMetric,
    const float* __restrict__ farList, const unsigned int* __restrict__ farCount,
    unsigned int farCap, float* __restrict__ out)
{
    __shared__ float4 sVal[WINSZ];           // (v0*m, v1*m, v2*m, m)   28224 B
    __shared__ unsigned int sPack[WINSZ];    // fracx | wy1<<16          7056 B
    __shared__ unsigned int sOff[NOFF];      // counts -> CSR offsets    4360 B
    __shared__ unsigned int sWsum[8];
    // total 39672 B -> 4 blocks/CU

    // XCD-aware bijective tile swizzle (8160 = 8*1020): each XCD gets a
    // contiguous band, tx fastest -> x-neighbor halos L2-hit.
    const int bid = blockIdx.x;
    const int lin = (bid & (NXCD - 1)) * TPX + (bid >> 3);
    const int tx  = lin % TXN;
    const int rem = lin / TXN;
    const int ty  = rem % TYN;
    const int n   = rem / TYN;

    const int tX = tx * TW, tY = ty * TH;
    const int tid = threadIdx.x;

    for (int j = tid; j < NOFF; j += 256) sOff[j] = 0u;
    __syncthreads();

    const float* __restrict__ f0 = tenFlow   + (size_t)(n * 2 + 0) * HW;
    const float* __restrict__ f1 = tenFlow   + (size_t)(n * 2 + 1) * HW;
    const float* __restrict__ mp = tenMetric + (size_t)n * HW;
    const float* __restrict__ i0 = tenIn + (size_t)(n * 3 + 0) * HW;
    const float* __restrict__ i1 = tenIn + (size_t)(n * 3 + 1) * HW;
    const float* __restrict__ i2 = tenIn + (size_t)(n * 3 + 2) * HW;

    // ---- phase 1: flow loads + bucket-count; value loads issued for
    //      bucketed chunks only (consumed in phase 3, 2 barriers later) ----
    unsigned int pk[2][4];    // sic<<16 | ci ; 0xFFFFFFFF = invalid
    unsigned int spw[2][4];   // packed (fracx, wy1)
    float4 rm4[2], ra0[2], ra1[2], ra2[2];

#pragma unroll
    for (int cc = 0; cc < 2; ++cc) {
#pragma unroll
        for (int k = 0; k < 4; ++k) pk[cc][k] = 0xFFFFFFFFu;
        int cidx = tid + cc * 256;
        if (cidx >= TOTCH) continue;
        int wy = cidx / NCHUNK;
        int cx = cidx - wy * NCHUNK;
        int sy = tY - REACH + wy;
        int gx = tX - PADL + cx * 4;              // 4-aligned; chunk fully in or out
        if (sy < 0 || sy >= Hh || gx < 0 || gx > Ww - 4) continue;
        int p = sy * Ww + gx;
        float4 fx4 = *(const float4*)(f0 + p);
        float4 fy4 = *(const float4*)(f1 + p);
        float fxa[4] = {fx4.x, fx4.y, fx4.z, fx4.w};
        float fya[4] = {fy4.x, fy4.y, fy4.z, fy4.w};
#pragma unroll
        for (int k = 0; k < 4; ++k) {
            int x = gx + k;
            if (x < tX - REACH || x >= tX + TW + REACH) continue;  // padding px
            float fxv = fxa[k], fyv = fya[k];
            if (!(fabsf(fxv) <= NEAR_MAX && fabsf(fyv) <= NEAR_MAX)) continue;  // NaN fails
            float fx = (float)x + fxv;
            float fy = (float)sy + fyv;
            float flx = floorf(fx), fly = floorf(fy);
            int lx0 = (int)flx - tX;
            int ly0 = (int)fly - tY;
            if (lx0 < -1 || lx0 >= TW || ly0 < -1 || ly0 >= TH) continue;
            int ci = (lx0 + 1) * NCH + (ly0 + 1);          // column-major
            unsigned int sic = atomicAdd(&sOff[ci], 1u);   // ds_add_rtn_u32
            pk[cc][k] = (sic << 16) | (unsigned int)ci;
            spw[cc][k] = __float2uint_rz((fx - flx) * 65536.0f)
                       | (__float2uint_rz((fy - fly) * 65536.0f) << 16);
        }
        unsigned int allv = pk[cc][0] & pk[cc][1] & pk[cc][2] & pk[cc][3];
        if (allv != 0xFFFFFFFFu) {            // >=1 bucketed px: issue value loads
            rm4[cc] = *(const float4*)(mp + p);
            ra0[cc] = *(const float4*)(i0 + p);
            ra1[cc] = *(const float4*)(i1 + p);
            ra2[cc] = *(const float4*)(i2 + p);
        }
    }
    __syncthreads();

    // ---- phase 2: exclusive prefix sum over sOff[0..NOFF) (218 threads x 5) ----
    unsigned int c0v = 0, c1v = 0, c2v = 0, c3v = 0, c4v = 0;
    if (tid < 218) {
        int base = tid * 5;
        c0v = sOff[base];     c1v = sOff[base + 1]; c2v = sOff[base + 2];
        c3v = sOff[base + 3]; c4v = sOff[base + 4];
    }
    unsigned int tsum = c0v + c1v + c2v + c3v + c4v;
    unsigned int incl = tsum;
#pragma unroll
    for (int d = 1; d < 64; d <<= 1) {
        unsigned int v = __shfl_up(incl, d);
        if ((tid & 63) >= d) incl += v;
    }
    const int wv = tid >> 6;
    if ((tid & 63) == 63) sWsum[wv] = incl;
    __syncthreads();                 // orders count-reads before off-writes too
    unsigned int woff = 0;
    {
        unsigned int w0 = sWsum[0], w1 = sWsum[1], w2 = sWsum[2];
        if (wv > 0) woff += w0;
        if (wv > 1) woff += w1;
        if (wv > 2) woff += w2;
    }
    unsigned int texcl = woff + incl - tsum;
    if (tid < 218) {
        int base = tid * 5;
        unsigned int o0 = texcl, o1 = o0 + c0v, o2 = o1 + c1v, o3 = o2 + c2v, o4 = o3 + c3v;
        sOff[base] = o0; sOff[base + 1] = o1; sOff[base + 2] = o2;
        sOff[base + 3] = o3; sOff[base + 4] = o4;
    }
    __syncthreads();

    // ---- phase 3: expf + premultiply + reg->LDS scatter (loads in flight) ----
#pragma unroll
    for (int cc = 0; cc < 2; ++cc) {
        unsigned int allv = pk[cc][0] & pk[cc][1] & pk[cc][2] & pk[cc][3];
        if (allv == 0xFFFFFFFFu) continue;
        float ma[4]  = {rm4[cc].x, rm4[cc].y, rm4[cc].z, rm4[cc].w};
        float a0a[4] = {ra0[cc].x, ra0[cc].y, ra0[cc].z, ra0[cc].w};
        float a1a[4] = {ra1[cc].x, ra1[cc].y, ra1[cc].z, ra1[cc].w};
        float a2a[4] = {ra2[cc].x, ra2[cc].y, ra2[cc].z, ra2[cc].w};
#pragma unroll
        for (int k = 0; k < 4; ++k) {
            unsigned int p_ = pk[cc][k];
            if (p_ == 0xFFFFFFFFu) continue;
            unsigned int ci  = p_ & 0xFFFFu;
            unsigned int sic = p_ >> 16;
            unsigned int slot = sOff[ci] + sic;
            float m = expf(ma[k]);
            sPack[slot] = spw[cc][k];
            sVal[slot]  = make_float4(a0a[k] * m, a1a[k] * m, a2a[k] * m, m);
        }
    }
    __syncthreads();

    // ---- phase 4: 5 contiguous row-pair ranges; row weight via s<mid ----
    const int r   = tid >> 3;        // 0..31 output row
    const int g   = tid & 7;
    const int cc0 = g * 4;           // first owned col

    float4 acc0 = make_float4(0.f, 0.f, 0.f, 0.f);
    float4 acc1 = make_float4(0.f, 0.f, 0.f, 0.f);
    float4 acc2 = make_float4(0.f, 0.f, 0.f, 0.f);
    float4 acc3 = make_float4(0.f, 0.f, 0.f, 0.f);

    // column j (cell col cc0+j; sources lx0 = cc0+j-1): L -> acc[j-1], R -> acc[j]
    // cell rows r (ly0=r-1, ay=wy1) then r+1 (ly0=r, ay=1-wy1), split at mid.
#define COLRANGE(J, HASL, HASR, ACCL, ACCR)                               \
    {                                                                     \
        const int cbase = (cc0 + (J)) * NCH + r;                          \
        unsigned int lo = sOff[cbase], md = sOff[cbase + 1],              \
                     hi = sOff[cbase + 2];                                \
        for (unsigned int s = lo; s < hi; ++s) {                          \
            unsigned int pw = sPack[s];                                   \
            float4 v = sVal[s];                                           \
            float fracx = (float)(pw & 0xFFFFu) * INV64K;                 \
            float wy1q  = (float)(pw >> 16)     * INV64K;                 \
            float ay = (s < md) ? wy1q : (1.0f - wy1q);                   \
            float wr = ay * fracx;                                        \
            float wl = ay - wr;                                           \
            if (HASL) { ACCL.x += v.x*wl; ACCL.y += v.y*wl;               \
                        ACCL.z += v.z*wl; ACCL.w += v.w*wl; }             \
            if (HASR) { ACCR.x += v.x*wr; ACCR.y += v.y*wr;               \
                        ACCR.z += v.z*wr; ACCR.w += v.w*wr; }             \
        }                                                                 \
    }

    COLRANGE(0, false, true,  acc0, acc0)
    COLRANGE(1, true,  true,  acc0, acc1)
    COLRANGE(2, true,  true,  acc1, acc2)
    COLRANGE(3, true,  true,  acc2, acc3)
    COLRANGE(4, true,  false, acc3, acc0)
#undef COLRANGE

    // ---- epilogue: far-list merge + normalize + write ----
    const int gy = tY + r;
    if (gy >= Hh) return;
    const int gx = tX + cc0;

    unsigned int fc = *farCount;
    if (fc > farCap) fc = farCap;
    const float gyf = (float)gy;
    const float gxf = (float)gx;
    for (unsigned int e = 0; e < fc; ++e) {
        const float* ep = farList + (size_t)e * 8;
        if (__float_as_int(ep[0]) != n) continue;
        float ffx = ep[1], ffy = ep[2];
        float ay = fmaxf(0.f, 1.f - fabsf(ffy - gyf));
        if (ay > 0.f) {
            float fv0 = ep[3], fv1 = ep[4], fv2 = ep[5], fm = ep[6];
            float d = ffx - gxf;
            float ax0 = fmaxf(0.f, 1.f - fabsf(d));
            float ax1 = fmaxf(0.f, 1.f - fabsf(d - 1.f));
            float ax2 = fmaxf(0.f, 1.f - fabsf(d - 2.f));
            float ax3 = fmaxf(0.f, 1.f - fabsf(d - 3.f));
            float w0 = ay * ax0, w1 = ay * ax1, w2 = ay * ax2, w3 = ay * ax3;
            acc0.x += fv0 * w0; acc0.y += fv1 * w0; acc0.z += fv2 * w0; acc0.w += fm * w0;
            acc1.x += fv0 * w1; acc1.y += fv1 * w1; acc1.z += fv2 * w1; acc1.w += fm * w1;
            acc2.x += fv0 * w2; acc2.y += fv1 * w2; acc2.z += fv2 * w2; acc2.w += fm * w2;
            acc3.x += fv0 * w3; acc3.y += fv1 * w3; acc3.z += fv2 * w3; acc3.w += fm * w3;
        }
    }

    const float inv0 = 1.0f / (acc0.w + EPS);
    const float inv1 = 1.0f / (acc1.w + EPS);
    const float inv2 = 1.0f / (acc2.w + EPS);
    const float inv3 = 1.0f / (acc3.w + EPS);

    const size_t pix = (size_t)gy * Ww + gx;   // gx % 4 == 0 -> 16B aligned
    float4 o;
    o = make_float4(acc0.x * inv0, acc1.x * inv1, acc2.x * inv2, acc3.x * inv3);
    *(float4*)(out + ((size_t)n * 3 + 0) * HW + pix) = o;
    o = make_float4(acc0.y * inv0, acc1.y * inv1, acc2.y * inv2, acc3.y * inv3);
    *(float4*)(out + ((size_t)n * 3 + 1) * HW + pix) = o;
    o = make_float4(acc0.z * inv0, acc1.z * inv1, acc2.z * inv2, acc3.z * inv3);
    *(float4*)(out + ((size_t)n * 3 + 2) * HW + pix) = o;
}

extern "C" void kernel_launch(void* const* d_in, const int* in_sizes, int n_in,
                              void* d_out, int out_size, void* d_ws, size_t ws_size,
                              hipStream_t stream) {
    const float* tenIn     = (const float*)d_in[0];
    const float* tenFlow   = (const float*)d_in[1];
    const float* tenMetric = (const float*)d_in[2];
    float* out = (float*)d_out;

    unsigned int* farCount = (unsigned int*)d_ws;
    float* farList = (float*)((char*)d_ws + 64);
    unsigned int farCap = (ws_size > 64) ? (unsigned int)((ws_size - 64) / 32) : 0;

    hipMemsetAsync(d_ws, 0, 64, stream);

    far_scatter<<<(TOTAL / 4 + 255) / 256, 256, 0, stream>>>(
        tenIn, tenFlow, tenMetric, farCount, farList, farCap);

    gather_splat<<<NTILES, 256, 0, stream>>>(
        tenIn, tenFlow, tenMetric, farList, farCount, farCap, out);
}